// Round 1
// baseline (19676.555 us; speedup 1.0000x reference)
//
#include <hip/hip_runtime.h>
#include <cstddef>

// LocalWindowTransformerBlock (Swin-style shifted-window block), fp32 baseline.
// B=16, H=W=64, C=384, HID=1536, HEADS=12, hd=32, WS=8, SHIFT=4.
// Phases:
//   1. ln1 + roll(-4,-4) + window partition -> ws0 (65536 x 384)
//   2. fused per-(window,head) attention (qkv+bias+rpb+mask+softmax+PV) -> ws1
//   3. proj GEMM + window-reverse + roll(+4,+4) + residual(x) -> d_out  (= x_attn)
//   4. ln2(d_out) -> ws0
//   5. per-2-batch: fc1 GEMM+BN1+GELU -> z1 ; dw3x3+BN2+GELU -> z2 ;
//      fc2 GEMM+BN3+GELU, += into d_out
// Workspace: ws0 = 100663296 B, ws1 = 100663296 B (z1/z2 reuse ws1). Total 192 MiB.

#define NTOK 65536   // B * L windowed tokens
#define CCH 384
#define HIDCH 1536

__device__ __forceinline__ float gelu_exact(float v) {
  return 0.5f * v * (1.0f + erff(v * 0.70710678118654752440f));
}

__device__ __forceinline__ int region_label(int p) {
  // rows/cols: [0,56)->0, [56,60)->1, [60,64)->2  (Hp=Wp=64, WS=8, SHIFT=4)
  return (p < 56) ? 0 : ((p < 60) ? 1 : 2);
}

// ---------------------------------------------------------------------------
// LayerNorm. REMAP=1: block t is a *windowed* token; source pixel found via
// roll(-4,-4). REMAP=0: plain per-token LN (input/output same token order).
// ---------------------------------------------------------------------------
template <int REMAP>
__global__ __launch_bounds__(384) void ln_kernel(const float* __restrict__ x,
                                                 const float* __restrict__ g,
                                                 const float* __restrict__ b,
                                                 float* __restrict__ y) {
  __shared__ float red[2][6];
  const int t = blockIdx.x;  // output token index
  size_t src;
  if (REMAP) {
    const int widx = t >> 6;      // (b, wh, ww)
    const int n = t & 63;         // token in window (r,s)
    const int bb = widx >> 6;
    const int wh = (widx >> 3) & 7;
    const int ww = widx & 7;
    const int hp = wh * 8 + (n >> 3);   // rolled-image row
    const int wp = ww * 8 + (n & 7);    // rolled-image col
    const int hs = (hp + 4) & 63;       // original row  (roll by -4)
    const int wsrc = (wp + 4) & 63;     // original col
    src = (size_t)bb * 4096 + hs * 64 + wsrc;
  } else {
    src = (size_t)t;
  }
  const int tid = threadIdx.x;  // 384 threads, one channel each
  const float v = x[src * CCH + tid];
  float s = v, s2 = v * v;
#pragma unroll
  for (int o = 1; o < 64; o <<= 1) {
    s += __shfl_xor(s, o);
    s2 += __shfl_xor(s2, o);
  }
  const int wid = tid >> 6;
  if ((tid & 63) == 0) {
    red[0][wid] = s;
    red[1][wid] = s2;
  }
  __syncthreads();
  float ts = 0.f, ts2 = 0.f;
#pragma unroll
  for (int i = 0; i < 6; ++i) {
    ts += red[0][i];
    ts2 += red[1][i];
  }
  const float mean = ts * (1.0f / 384.0f);
  const float var = ts2 * (1.0f / 384.0f) - mean * mean;
  const float rstd = rsqrtf(var + 1e-5f);
  y[(size_t)t * CCH + tid] = (v - mean) * rstd * g[tid] + b[tid];
}

// ---------------------------------------------------------------------------
// Fused attention: one block per (window, head). 256 threads.
// LDS: y chunk (64x64, stride 65) + q/k/v (64x32, stride 33) + attn (64x64,
// stride 65) = 57 KiB (< 64 KiB static limit, 2 blocks/CU w.r.t. 160 KiB LDS).
// ---------------------------------------------------------------------------
__global__ __launch_bounds__(256) void attn_kernel(
    const float* __restrict__ y,      // (65536, 384) windowed LN1 output
    const float* __restrict__ qkv_w,  // (1152, 384)
    const float* __restrict__ qkv_b,  // (1152)
    const float* __restrict__ rpb,    // (225, 12)
    float* __restrict__ ao) {         // (65536, 384)
  __shared__ float ys[64][65];
  __shared__ float qs[64][33];
  __shared__ float ks[64][33];
  __shared__ float vs[64][33];
  __shared__ float at[64][65];

  const int widx = blockIdx.x / 12;
  const int head = blockIdx.x % 12;
  const int tid = threadIdx.x;

  // ---- QKV projection: acc over 6 chunks of 64 channels ----
  float acc[24];
#pragma unroll
  for (int i = 0; i < 24; ++i) acc[i] = 0.f;

  for (int c0 = 0; c0 < CCH; c0 += 64) {
#pragma unroll
    for (int i = 0; i < 16; ++i) {
      const int e = tid + i * 256;
      const int r = e >> 6, c = e & 63;
      ys[r][c] = y[((size_t)widx * 64 + r) * CCH + c0 + c];
    }
    __syncthreads();
#pragma unroll
    for (int i = 0; i < 24; ++i) {
      const int e = tid + i * 256;       // 0..6143
      const int mm = e >> 11;            // 0=q 1=k 2=v
      const int rem = e & 2047;
      const int n = rem >> 5;
      const int d = rem & 31;
      const float* wr = qkv_w + ((size_t)(mm * 384 + head * 32 + d)) * CCH + c0;
      float a = 0.f;
#pragma unroll
      for (int c = 0; c < 64; ++c) a += ys[n][c] * wr[c];
      acc[i] += a;
    }
    __syncthreads();
  }

  const float scale = 0.17677669529663687f;  // 32^-0.5
#pragma unroll
  for (int i = 0; i < 24; ++i) {
    const int e = tid + i * 256;
    const int mm = e >> 11;
    const int rem = e & 2047;
    const int n = rem >> 5;
    const int d = rem & 31;
    const float val = acc[i] + qkv_b[mm * 384 + head * 32 + d];
    if (mm == 0)
      qs[n][d] = val * scale;
    else if (mm == 1)
      ks[n][d] = val;
    else
      vs[n][d] = val;
  }
  __syncthreads();

  // ---- logits: q.k + rel-pos bias + shift mask ----
  const int wh = (widx >> 3) & 7;
  const int ww = widx & 7;
#pragma unroll
  for (int i = 0; i < 16; ++i) {
    const int e = tid + i * 256;
    const int n = e >> 6, m = e & 63;
    float a = 0.f;
#pragma unroll
    for (int d = 0; d < 32; ++d) a += qs[n][d] * ks[m][d];
    // rel pos: coords[t] = 15*(t/8) + t%8 ; idx = coords[n] + coords[63-m]
    const int cn = 15 * (n >> 3) + (n & 7);
    const int mf = 63 - m;
    const int cm = 15 * (mf >> 3) + (mf & 7);
    a += rpb[(cn + cm) * 12 + head];
    // shift mask (labels on rolled image)
    const int hn = wh * 8 + (n >> 3), wn = ww * 8 + (n & 7);
    const int hm = wh * 8 + (m >> 3), wm = ww * 8 + (m & 7);
    const int ln_ = region_label(hn) * 3 + region_label(wn);
    const int lm_ = region_label(hm) * 3 + region_label(wm);
    if (ln_ != lm_) a -= 100.f;
    at[n][m] = a;
  }
  __syncthreads();

  // ---- softmax: 4 lanes per row (row = tid>>2 stays within one wave group) ----
  {
    const int row = tid >> 2, p = tid & 3;
    float mx = -1e30f;
    float ev[16];
#pragma unroll
    for (int j = 0; j < 16; ++j) mx = fmaxf(mx, at[row][p * 16 + j]);
    mx = fmaxf(mx, __shfl_xor(mx, 1));
    mx = fmaxf(mx, __shfl_xor(mx, 2));
    float sum = 0.f;
#pragma unroll
    for (int j = 0; j < 16; ++j) {
      ev[j] = expf(at[row][p * 16 + j] - mx);
      sum += ev[j];
    }
    sum += __shfl_xor(sum, 1);
    sum += __shfl_xor(sum, 2);
    const float inv = 1.0f / sum;
#pragma unroll
    for (int j = 0; j < 16; ++j) at[row][p * 16 + j] = ev[j] * inv;
  }
  __syncthreads();

  // ---- PV ----
#pragma unroll
  for (int i = 0; i < 8; ++i) {
    const int e = tid + i * 256;  // 0..2047
    const int n = e >> 5, d = e & 31;
    float a = 0.f;
#pragma unroll
    for (int m = 0; m < 64; ++m) a += at[n][m] * vs[m][d];
    ao[((size_t)widx * 64 + n) * CCH + head * 32 + d] = a;
  }
}

// ---------------------------------------------------------------------------
// Tiled fp32 GEMM: C = A(MxK) @ W(NxK)^T + bias, 64x64x32 tile, 4x4/thread.
// MODE 0: proj  -> window-reverse+roll remap, Cout[dst] = Xres[dst] + val
// MODE 1: fc1   -> Cout[r*N+c]  = gelu(bn(val))
// MODE 2: fc2   -> Cout[r*N+c] += gelu(bn(val))
// ---------------------------------------------------------------------------
template <int MODE>
__global__ __launch_bounds__(256) void gemm_kernel(
    const float* __restrict__ A, const float* __restrict__ Wm,
    const float* __restrict__ bias, float* __restrict__ Cout,
    const float* __restrict__ Xres, const float* __restrict__ bng,
    const float* __restrict__ bnb, int N, int K) {
  __shared__ float As[32][68];
  __shared__ float Bs[32][68];
  const int m0 = blockIdx.x * 64;
  const int n0 = blockIdx.y * 64;
  const int tid = threadIdx.x;
  const int tx = tid & 15, ty = tid >> 4;
  float accv[4][4];
#pragma unroll
  for (int i = 0; i < 4; ++i)
#pragma unroll
    for (int j = 0; j < 4; ++j) accv[i][j] = 0.f;

  for (int k0 = 0; k0 < K; k0 += 32) {
#pragma unroll
    for (int i = 0; i < 8; ++i) {
      const int e = tid + i * 256;
      const int r = e >> 5, kk = e & 31;
      As[kk][r] = A[(size_t)(m0 + r) * K + k0 + kk];
      Bs[kk][r] = Wm[(size_t)(n0 + r) * K + k0 + kk];
    }
    __syncthreads();
#pragma unroll
    for (int k = 0; k < 32; ++k) {
      const float4 av = *(const float4*)&As[k][ty * 4];
      const float4 bv = *(const float4*)&Bs[k][tx * 4];
      const float a4[4] = {av.x, av.y, av.z, av.w};
      const float b4[4] = {bv.x, bv.y, bv.z, bv.w};
#pragma unroll
      for (int i = 0; i < 4; ++i)
#pragma unroll
        for (int j = 0; j < 4; ++j) accv[i][j] += a4[i] * b4[j];
    }
    __syncthreads();
  }

  const float RSQ = 0.99999500003749969f;  // 1/sqrt(1+1e-5)
#pragma unroll
  for (int i = 0; i < 4; ++i) {
    const int r = m0 + ty * 4 + i;
#pragma unroll
    for (int j = 0; j < 4; ++j) {
      const int c = n0 + tx * 4 + j;
      const float val = accv[i][j] + bias[c];
      if (MODE == 0) {
        const int widx = r >> 6, n = r & 63;
        const int bb = widx >> 6, wh = (widx >> 3) & 7, wwi = widx & 7;
        const int hp = wh * 8 + (n >> 3), wp = wwi * 8 + (n & 7);
        const int hh = (hp + 4) & 63, wwp = (wp + 4) & 63;
        const size_t dst = ((size_t)bb * 4096 + hh * 64 + wwp) * CCH + c;
        Cout[dst] = Xres[dst] + val;
      } else {
        const float vbn = val * (bng[c] * RSQ) + bnb[c];
        const float ge = gelu_exact(vbn);
        if (MODE == 1)
          Cout[(size_t)r * N + c] = ge;
        else
          Cout[(size_t)r * N + c] += ge;
      }
    }
  }
}

// ---------------------------------------------------------------------------
// Depthwise 3x3 SAME + bias + BN2 + GELU, NHWC (c contiguous). 2 batches/grid.
// ---------------------------------------------------------------------------
__global__ __launch_bounds__(256) void dw_kernel(
    const float* __restrict__ z1, const float* __restrict__ dww,
    const float* __restrict__ dwb, const float* __restrict__ bn2g,
    const float* __restrict__ bn2b, float* __restrict__ z2) {
  const int pix = blockIdx.x;            // 0..8191 (2 batches)
  const int p = pix & 4095;
  const int h = p >> 6, w = p & 63;
  const float* zb = z1 + (size_t)(pix >> 12) * 4096 * HIDCH;
  const float RSQ = 0.99999500003749969f;
  for (int c = threadIdx.x; c < HIDCH; c += 256) {
    float a = dwb[c];
#pragma unroll
    for (int dh = -1; dh <= 1; ++dh) {
      const int hh = h + dh;
      if (hh < 0 || hh > 63) continue;
#pragma unroll
      for (int dwx = -1; dwx <= 1; ++dwx) {
        const int wn = w + dwx;
        if (wn < 0 || wn > 63) continue;
        a += zb[((size_t)hh * 64 + wn) * HIDCH + c] *
             dww[c * 9 + (dh + 1) * 3 + (dwx + 1)];
      }
    }
    const float vbn = a * (bn2g[c] * RSQ) + bn2b[c];
    z2[(size_t)pix * HIDCH + c] = gelu_exact(vbn);
  }
}

extern "C" void kernel_launch(void* const* d_in, const int* in_sizes, int n_in,
                              void* d_out, int out_size, void* d_ws,
                              size_t ws_size, hipStream_t stream) {
  const float* x = (const float*)d_in[0];
  const float* ln1_g = (const float*)d_in[3];
  const float* ln1_b = (const float*)d_in[4];
  const float* qkv_w = (const float*)d_in[5];
  const float* qkv_b = (const float*)d_in[6];
  const float* rpb = (const float*)d_in[7];
  const float* proj_w = (const float*)d_in[8];
  const float* proj_b = (const float*)d_in[9];
  const float* ln2_g = (const float*)d_in[10];
  const float* ln2_b = (const float*)d_in[11];
  const float* fc1_w = (const float*)d_in[12];
  const float* fc1_b = (const float*)d_in[13];
  const float* bn1_g = (const float*)d_in[14];
  const float* bn1_b = (const float*)d_in[15];
  const float* dw_w = (const float*)d_in[16];
  const float* dw_b = (const float*)d_in[17];
  const float* bn2_g = (const float*)d_in[18];
  const float* bn2_b = (const float*)d_in[19];
  const float* fc2_w = (const float*)d_in[20];
  const float* fc2_b = (const float*)d_in[21];
  const float* bn3_g = (const float*)d_in[22];
  const float* bn3_b = (const float*)d_in[23];
  float* out = (float*)d_out;

  float* ws0 = (float*)d_ws;                   // 65536*384 = 100.7 MB
  float* ws1 = ws0 + (size_t)NTOK * CCH;       // 65536*384 = 100.7 MB

  // 1. LN1 + roll + window partition
  ln_kernel<1><<<NTOK, 384, 0, stream>>>(x, ln1_g, ln1_b, ws0);
  // 2. fused attention
  attn_kernel<<<1024 * 12, 256, 0, stream>>>(ws0, qkv_w, qkv_b, rpb, ws1);
  // 3. proj + unwindow + unroll + residual -> d_out (= x_attn)
  gemm_kernel<0><<<dim3(NTOK / 64, CCH / 64), 256, 0, stream>>>(
      ws1, proj_w, proj_b, out, x, nullptr, nullptr, CCH, CCH);
  // 4. LN2
  ln_kernel<0><<<NTOK, 384, 0, stream>>>(out, ln2_g, ln2_b, ws0);
  // 5. MLP in 2-batch chunks (z1/z2 reuse ws1: 2*4096*1536 floats each)
  float* z1 = ws1;
  float* z2 = ws1 + (size_t)2 * 4096 * HIDCH;
  for (int b = 0; b < 16; b += 2) {
    const float* hb = ws0 + (size_t)b * 4096 * CCH;
    gemm_kernel<1><<<dim3(2 * 4096 / 64, HIDCH / 64), 256, 0, stream>>>(
        hb, fc1_w, fc1_b, z1, nullptr, bn1_g, bn1_b, HIDCH, CCH);
    dw_kernel<<<8192, 256, 0, stream>>>(z1, dw_w, dw_b, bn2_g, bn2_b, z2);
    gemm_kernel<2><<<dim3(2 * 4096 / 64, CCH / 64), 256, 0, stream>>>(
        z2, fc2_w, fc2_b, out + (size_t)b * 4096 * CCH, nullptr, bn3_g, bn3_b,
        CCH, HIDCH);
  }
}

// Round 2
// 2450.441 us; speedup vs baseline: 8.0298x; 8.0298x over previous
//
#include <hip/hip_runtime.h>
#include <cstddef>

// Swin shifted-window block, bf16-MFMA version.
// B=16, H=W=64, C=384, HID=1536, HEADS=12, hd=32, WS=8, SHIFT=4.
//
// Pipeline:
//   0. convert weights (qkv/proj/fc1/fc2) fp32 -> bf16 into ws
//   1. ln1 + roll(-4,-4) + window partition -> wsA (bf16, 65536x384)
//   2. per-4-batch chunk: QKV bf16-MFMA GEMM -> wsQ ; slim attention
//      (logits+rpb+mask+softmax+PV) -> wsAO (bf16)
//   3. proj MFMA GEMM + unwindow + unroll + residual(x) -> d_out (fp32)
//   4. ln2(d_out) -> wsA (bf16)
//   5. per-4-batch chunk: fc1 MFMA+BN+GELU -> z1(bf16) ; dw3x3+BN+GELU ->
//      z2(bf16) ; fc2 MFMA+BN+GELU += d_out
//
// ws layout (bytes):
//   [0,           50331648)   wsA   : LN1 out / LN2 out
//   [50331648,   100663296)   wsAO  : attn out / z1
//   [100663296,  150994944)   wsQ   : qkv chunk / z2
//   [150994944,  154533888)   wbf   : bf16 weights
// peak 154.5 MB (round-1 proved >= 192 MiB available).

#define CCH 384
#define HIDCH 1536

typedef __attribute__((ext_vector_type(8))) short short8;
typedef __attribute__((ext_vector_type(4))) float f32x4;

__device__ __forceinline__ float gelu_exact(float v) {
  return 0.5f * v * (1.0f + erff(v * 0.70710678118654752440f));
}
__device__ __forceinline__ unsigned short f2bf(float f) {
  unsigned u = __builtin_bit_cast(unsigned, f);
  u = (u + 0x7FFF + ((u >> 16) & 1)) >> 16;
  return (unsigned short)u;
}
__device__ __forceinline__ float bf2f(unsigned short s) {
  return __builtin_bit_cast(float, (unsigned)s << 16);
}
__device__ __forceinline__ int region_label(int p) {
  return (p < 56) ? 0 : ((p < 60) ? 1 : 2);
}

// ---------------------------------------------------------------------------
__global__ __launch_bounds__(256) void convw_kernel(
    const float* __restrict__ a, const float* __restrict__ b,
    const float* __restrict__ c, const float* __restrict__ d,
    unsigned short* __restrict__ o) {
  const int i = blockIdx.x * 256 + threadIdx.x;
  // 442368 + 147456 + 589824 + 589824 = 1769472
  if (i >= 1769472) return;
  float v;
  if (i < 442368) v = a[i];
  else if (i < 589824) v = b[i - 442368];
  else if (i < 1179648) v = c[i - 589824];
  else v = d[i - 1179648];
  o[i] = f2bf(v);
}

// ---------------------------------------------------------------------------
// LayerNorm -> bf16. REMAP=1: out token is windowed/rolled; src via roll(+4).
// ---------------------------------------------------------------------------
template <int REMAP>
__global__ __launch_bounds__(384) void ln_kernel(const float* __restrict__ x,
                                                 const float* __restrict__ g,
                                                 const float* __restrict__ b,
                                                 unsigned short* __restrict__ y) {
  __shared__ float red[2][6];
  const int t = blockIdx.x;
  size_t src;
  if (REMAP) {
    const int widx = t >> 6;
    const int n = t & 63;
    const int bb = widx >> 6;
    const int wh = (widx >> 3) & 7;
    const int ww = widx & 7;
    const int hp = wh * 8 + (n >> 3);
    const int wp = ww * 8 + (n & 7);
    const int hs = (hp + 4) & 63;
    const int wsrc = (wp + 4) & 63;
    src = (size_t)bb * 4096 + hs * 64 + wsrc;
  } else {
    src = (size_t)t;
  }
  const int tid = threadIdx.x;
  const float v = x[src * CCH + tid];
  float s = v, s2 = v * v;
#pragma unroll
  for (int o = 1; o < 64; o <<= 1) {
    s += __shfl_xor(s, o);
    s2 += __shfl_xor(s2, o);
  }
  const int wid = tid >> 6;
  if ((tid & 63) == 0) {
    red[0][wid] = s;
    red[1][wid] = s2;
  }
  __syncthreads();
  float ts = 0.f, ts2 = 0.f;
#pragma unroll
  for (int i = 0; i < 6; ++i) {
    ts += red[0][i];
    ts2 += red[1][i];
  }
  const float mean = ts * (1.0f / 384.0f);
  const float var = ts2 * (1.0f / 384.0f) - mean * mean;
  const float rstd = rsqrtf(var + 1e-5f);
  y[(size_t)t * CCH + tid] = f2bf((v - mean) * rstd * g[tid] + b[tid]);
}

// ---------------------------------------------------------------------------
// bf16 MFMA GEMM: C = A(MxK,bf16) @ W(NxK,bf16)^T + bias.
// 128x128 tile, 256 thr = 4 waves (2x2 of 64x64), 4x4 MFMA 16x16x32 per wave.
// MODE 0: qkv  -> bf16 store (r*N+c)
// MODE 1: proj -> fp32, window-reverse+roll remap, Cout[dst] = Xres[dst]+val
// MODE 2: fc1  -> bf16, gelu(bn(val))
// MODE 3: fc2  -> fp32, Cout[r*N+c] += gelu(bn(val))
// ---------------------------------------------------------------------------
template <int MODE>
__global__ __launch_bounds__(256) void mfma_gemm(
    const unsigned short* __restrict__ A, const unsigned short* __restrict__ W,
    const float* __restrict__ bias, void* __restrict__ CoutV,
    const float* __restrict__ Xres, const float* __restrict__ bng,
    const float* __restrict__ bnb, int N, int K) {
  __shared__ __align__(16) unsigned short As[128 * 32];
  __shared__ __align__(16) unsigned short Bs[128 * 32];
  const int tid = threadIdx.x;
  const int wave = tid >> 6, lane = tid & 63;
  const int qd = lane >> 4, ln16 = lane & 15;
  const int wm = wave >> 1, wn = wave & 1;
  const int m0 = blockIdx.x * 128;
  const int n0 = blockIdx.y * 128;

  f32x4 acc[4][4];
#pragma unroll
  for (int i = 0; i < 4; ++i)
#pragma unroll
    for (int j = 0; j < 4; ++j) acc[i][j] = (f32x4){0.f, 0.f, 0.f, 0.f};

  const int r = tid >> 2;             // 0..63
  const int ck = (tid & 3) * 8;       // k element offset of 16B chunk

  for (int k0 = 0; k0 < K; k0 += 32) {
    const int4 a0 = *(const int4*)&A[(size_t)(m0 + r) * K + k0 + ck];
    const int4 a1 = *(const int4*)&A[(size_t)(m0 + 64 + r) * K + k0 + ck];
    const int4 b0 = *(const int4*)&W[(size_t)(n0 + r) * K + k0 + ck];
    const int4 b1 = *(const int4*)&W[(size_t)(n0 + 64 + r) * K + k0 + ck];
    __syncthreads();
    *(int4*)&As[(size_t)tid * 8] = a0;
    *(int4*)&As[2048 + (size_t)tid * 8] = a1;
    *(int4*)&Bs[(size_t)tid * 8] = b0;
    *(int4*)&Bs[2048 + (size_t)tid * 8] = b1;
    __syncthreads();
    short8 af[4], bfr[4];
#pragma unroll
    for (int mt = 0; mt < 4; ++mt)
      af[mt] = *(const short8*)&As[(wm * 64 + mt * 16 + ln16) * 32 + qd * 8];
#pragma unroll
    for (int nt = 0; nt < 4; ++nt)
      bfr[nt] = *(const short8*)&Bs[(wn * 64 + nt * 16 + ln16) * 32 + qd * 8];
#pragma unroll
    for (int mt = 0; mt < 4; ++mt)
#pragma unroll
      for (int nt = 0; nt < 4; ++nt)
        acc[mt][nt] = __builtin_amdgcn_mfma_f32_16x16x32_bf16(
            af[mt], bfr[nt], acc[mt][nt], 0, 0, 0);
  }

  const float RSQ = 0.99999500003749969f;  // 1/sqrt(1+1e-5)
#pragma unroll
  for (int mt = 0; mt < 4; ++mt) {
#pragma unroll
    for (int nt = 0; nt < 4; ++nt) {
      const int col = n0 + wn * 64 + nt * 16 + ln16;
      const int rbase = m0 + wm * 64 + mt * 16 + qd * 4;
#pragma unroll
      for (int rg = 0; rg < 4; ++rg) {
        const int row = rbase + rg;
        const float val = acc[mt][nt][rg] + bias[col];
        if (MODE == 0) {
          ((unsigned short*)CoutV)[(size_t)row * N + col] = f2bf(val);
        } else if (MODE == 1) {
          const int widx = row >> 6, n = row & 63;
          const int bb = widx >> 6, wh = (widx >> 3) & 7, wwi = widx & 7;
          const int hp = wh * 8 + (n >> 3), wp = wwi * 8 + (n & 7);
          const int hh = (hp + 4) & 63, wwp = (wp + 4) & 63;
          const size_t dst = ((size_t)bb * 4096 + hh * 64 + wwp) * CCH + col;
          ((float*)CoutV)[dst] = Xres[dst] + val;
        } else {
          const float vbn = val * (bng[col] * RSQ) + bnb[col];
          const float ge = gelu_exact(vbn);
          if (MODE == 2) {
            ((unsigned short*)CoutV)[(size_t)row * N + col] = f2bf(ge);
          } else {
            float* o = (float*)CoutV + (size_t)row * N + col;
            *o = *o + ge;
          }
        }
      }
    }
  }
}

// ---------------------------------------------------------------------------
// Slim attention: one block per (window-in-chunk, head). q/k/v from bf16
// qkv buffer (Mc x 1152). LDS ~42 KiB.
// ---------------------------------------------------------------------------
__global__ __launch_bounds__(256) void attn_kernel(
    const unsigned short* __restrict__ qkv, const float* __restrict__ rpb,
    unsigned short* __restrict__ ao) {
  __shared__ float qs[64][33];
  __shared__ float ks[64][33];
  __shared__ float vs[64][33];
  __shared__ float at[64][65];
  const int wloc = blockIdx.x / 12;   // window within chunk (0..255)
  const int head = blockIdx.x % 12;
  const int tid = threadIdx.x;
  const int wpos = wloc & 63;         // window position in image
  const int wh = (wpos >> 3) & 7, ww = wpos & 7;

  {
    const int n = tid >> 2, d0 = (tid & 3) * 8;
    const float scale = 0.17677669529663687f;  // 32^-0.5
    const size_t base = ((size_t)wloc * 64 + n) * 1152 + head * 32 + d0;
    const unsigned short* qp = qkv + base;
    const unsigned short* kp = qkv + base + 384;
    const unsigned short* vp = qkv + base + 768;
#pragma unroll
    for (int j = 0; j < 8; ++j) qs[n][d0 + j] = bf2f(qp[j]) * scale;
#pragma unroll
    for (int j = 0; j < 8; ++j) ks[n][d0 + j] = bf2f(kp[j]);
#pragma unroll
    for (int j = 0; j < 8; ++j) vs[n][d0 + j] = bf2f(vp[j]);
  }
  __syncthreads();

#pragma unroll
  for (int i = 0; i < 16; ++i) {
    const int e = tid + i * 256;
    const int n = e >> 6, m = e & 63;
    float a = 0.f;
#pragma unroll
    for (int d = 0; d < 32; ++d) a += qs[n][d] * ks[m][d];
    const int cn = 15 * (n >> 3) + (n & 7);
    const int mf = 63 - m;
    const int cm = 15 * (mf >> 3) + (mf & 7);
    a += rpb[(cn + cm) * 12 + head];
    const int hn = wh * 8 + (n >> 3), wn_ = ww * 8 + (n & 7);
    const int hm = wh * 8 + (m >> 3), wmm = ww * 8 + (m & 7);
    if (region_label(hn) * 3 + region_label(wn_) !=
        region_label(hm) * 3 + region_label(wmm))
      a -= 100.f;
    at[n][m] = a;
  }
  __syncthreads();

  {
    const int row = tid >> 2, p = tid & 3;
    float mx = -1e30f;
    float ev[16];
#pragma unroll
    for (int j = 0; j < 16; ++j) mx = fmaxf(mx, at[row][p * 16 + j]);
    mx = fmaxf(mx, __shfl_xor(mx, 1));
    mx = fmaxf(mx, __shfl_xor(mx, 2));
    float sum = 0.f;
#pragma unroll
    for (int j = 0; j < 16; ++j) {
      ev[j] = expf(at[row][p * 16 + j] - mx);
      sum += ev[j];
    }
    sum += __shfl_xor(sum, 1);
    sum += __shfl_xor(sum, 2);
    const float inv = 1.0f / sum;
#pragma unroll
    for (int j = 0; j < 16; ++j) at[row][p * 16 + j] = ev[j] * inv;
  }
  __syncthreads();

#pragma unroll
  for (int i = 0; i < 8; ++i) {
    const int e = tid + i * 256;
    const int n = e >> 5, d = e & 31;
    float a = 0.f;
#pragma unroll
    for (int m = 0; m < 64; ++m) a += at[n][m] * vs[m][d];
    ao[((size_t)wloc * 64 + n) * CCH + head * 32 + d] = f2bf(a);
  }
}

// ---------------------------------------------------------------------------
// Depthwise 3x3 SAME + bias + BN2 + GELU, bf16 in/out. 4 batches per grid.
// ---------------------------------------------------------------------------
__global__ __launch_bounds__(256) void dw_kernel(
    const unsigned short* __restrict__ z1, const float* __restrict__ dww,
    const float* __restrict__ dwb, const float* __restrict__ bn2g,
    const float* __restrict__ bn2b, unsigned short* __restrict__ z2) {
  const int pix = blockIdx.x;  // 0..16383
  const int p = pix & 4095;
  const int h = p >> 6, w = p & 63;
  const unsigned short* zb = z1 + (size_t)(pix >> 12) * 4096 * HIDCH;
  const float RSQ = 0.99999500003749969f;
  for (int c = threadIdx.x; c < HIDCH; c += 256) {
    float a = dwb[c];
#pragma unroll
    for (int dh = -1; dh <= 1; ++dh) {
      const int hh = h + dh;
      if (hh < 0 || hh > 63) continue;
#pragma unroll
      for (int dx = -1; dx <= 1; ++dx) {
        const int wn = w + dx;
        if (wn < 0 || wn > 63) continue;
        a += bf2f(zb[((size_t)hh * 64 + wn) * HIDCH + c]) *
             dww[c * 9 + (dh + 1) * 3 + (dx + 1)];
      }
    }
    const float vbn = a * (bn2g[c] * RSQ) + bn2b[c];
    z2[(size_t)pix * HIDCH + c] = f2bf(gelu_exact(vbn));
  }
}

extern "C" void kernel_launch(void* const* d_in, const int* in_sizes, int n_in,
                              void* d_out, int out_size, void* d_ws,
                              size_t ws_size, hipStream_t stream) {
  const float* x = (const float*)d_in[0];
  const float* ln1_g = (const float*)d_in[3];
  const float* ln1_b = (const float*)d_in[4];
  const float* qkv_w = (const float*)d_in[5];
  const float* qkv_b = (const float*)d_in[6];
  const float* rpb = (const float*)d_in[7];
  const float* proj_w = (const float*)d_in[8];
  const float* proj_b = (const float*)d_in[9];
  const float* ln2_g = (const float*)d_in[10];
  const float* ln2_b = (const float*)d_in[11];
  const float* fc1_w = (const float*)d_in[12];
  const float* fc1_b = (const float*)d_in[13];
  const float* bn1_g = (const float*)d_in[14];
  const float* bn1_b = (const float*)d_in[15];
  const float* dw_w = (const float*)d_in[16];
  const float* dw_b = (const float*)d_in[17];
  const float* bn2_g = (const float*)d_in[18];
  const float* bn2_b = (const float*)d_in[19];
  const float* fc2_w = (const float*)d_in[20];
  const float* fc2_b = (const float*)d_in[21];
  const float* bn3_g = (const float*)d_in[22];
  const float* bn3_b = (const float*)d_in[23];
  float* out = (float*)d_out;

  char* ws = (char*)d_ws;
  unsigned short* wsA = (unsigned short*)ws;                    // 50.3 MB
  unsigned short* wsAO = (unsigned short*)(ws + 50331648);      // 50.3 MB
  unsigned short* wsQ = (unsigned short*)(ws + 100663296);      // 50.3 MB
  unsigned short* wbf = (unsigned short*)(ws + 150994944);      // 3.5 MB
  unsigned short* w_qkv = wbf;
  unsigned short* w_proj = wbf + 442368;
  unsigned short* w_fc1 = wbf + 589824;
  unsigned short* w_fc2 = wbf + 1179648;

  // 0. weights -> bf16
  convw_kernel<<<6912, 256, 0, stream>>>(qkv_w, proj_w, fc1_w, fc2_w, wbf);
  // 1. LN1 + roll + window partition
  ln_kernel<1><<<65536, 384, 0, stream>>>(x, ln1_g, ln1_b, wsA);
  // 2. QKV GEMM + attention per 4-batch chunk (16384 tokens)
  for (int cb = 0; cb < 4; ++cb) {
    mfma_gemm<0><<<dim3(128, 9), 256, 0, stream>>>(
        wsA + (size_t)cb * 16384 * CCH, w_qkv, qkv_b, wsQ, nullptr, nullptr,
        nullptr, 1152, CCH);
    attn_kernel<<<256 * 12, 256, 0, stream>>>(
        wsQ, rpb, wsAO + (size_t)cb * 16384 * CCH);
  }
  // 3. proj + unwindow + unroll + residual -> d_out
  mfma_gemm<1><<<dim3(512, 3), 256, 0, stream>>>(wsAO, w_proj, proj_b, out, x,
                                                 nullptr, nullptr, CCH, CCH);
  // 4. LN2 -> wsA
  ln_kernel<0><<<65536, 384, 0, stream>>>(out, ln2_g, ln2_b, wsA);
  // 5. MLP per 4-batch chunk; z1 = wsAO, z2 = wsQ
  for (int cb = 0; cb < 4; ++cb) {
    mfma_gemm<2><<<dim3(128, 12), 256, 0, stream>>>(
        wsA + (size_t)cb * 16384 * CCH, w_fc1, fc1_b, wsAO, nullptr, bn1_g,
        bn1_b, HIDCH, CCH);
    dw_kernel<<<16384, 256, 0, stream>>>(wsAO, dw_w, dw_b, bn2_g, bn2_b, wsQ);
    mfma_gemm<3><<<dim3(128, 3), 256, 0, stream>>>(
        wsQ, w_fc2, fc2_b, out + (size_t)cb * 16384 * CCH, nullptr, bn3_g,
        bn3_b, CCH, HIDCH);
  }
}

// Round 3
// 1709.450 us; speedup vs baseline: 11.5105x; 1.4335x over previous
//
#include <hip/hip_runtime.h>
#include <cstddef>

// Swin shifted-window block, bf16-MFMA version, round 3.
// Changes vs round 2:
//  - dw_kernel: 8-channel int4 vectorization (16B/lane loads/stores),
//    dw weights pre-transposed to [tap][1536] for coalesced float4 loads.
//  - mfma_gemm: global->LDS staging via __builtin_amdgcn_global_load_lds
//    (width 16), removing the VGPR round-trip (m97 pattern).
//
// ws layout (bytes):
//   [0,           50331648)   wsA   : LN1 out / LN2 out (bf16)
//   [50331648,   100663296)   wsAO  : attn out / z1 (bf16)
//   [100663296,  150994944)   wsQ   : qkv chunk / z2 (bf16)
//   [150994944,  154533888)   wbf   : bf16 weights
//   [154533888,  154589184)   dwt   : fp32 dw weights [9][1536]
// peak ~147.4 MiB.

#define CCH 384
#define HIDCH 1536

typedef __attribute__((ext_vector_type(8))) short short8;
typedef __attribute__((ext_vector_type(4))) float f32x4;

__device__ __forceinline__ float gelu_exact(float v) {
  return 0.5f * v * (1.0f + erff(v * 0.70710678118654752440f));
}
__device__ __forceinline__ unsigned short f2bf(float f) {
  unsigned u = __builtin_bit_cast(unsigned, f);
  u = (u + 0x7FFF + ((u >> 16) & 1)) >> 16;
  return (unsigned short)u;
}
__device__ __forceinline__ float bf2f(unsigned short s) {
  return __builtin_bit_cast(float, (unsigned)s << 16);
}
__device__ __forceinline__ int region_label(int p) {
  return (p < 56) ? 0 : ((p < 60) ? 1 : 2);
}

// async global->LDS, 16B per lane. LDS dest = wave-uniform base + lane*16.
__device__ __forceinline__ void gl_lds16(const void* g, void* l) {
  __builtin_amdgcn_global_load_lds(
      (const __attribute__((address_space(1))) unsigned int*)g,
      (__attribute__((address_space(3))) unsigned int*)l, 16, 0, 0);
}

// ---------------------------------------------------------------------------
// Weight prep: fp32->bf16 for qkv/proj/fc1/fc2, plus dw transpose to
// dwt[tap*1536 + c] = dw_w[c*9 + tap] (fp32).
// ---------------------------------------------------------------------------
__global__ __launch_bounds__(256) void convw_kernel(
    const float* __restrict__ a, const float* __restrict__ b,
    const float* __restrict__ c, const float* __restrict__ d,
    const float* __restrict__ dww, unsigned short* __restrict__ o,
    float* __restrict__ dwt) {
  const int i = blockIdx.x * 256 + threadIdx.x;
  // 442368 + 147456 + 589824 + 589824 = 1769472 bf16 weights, then 13824 dwt
  if (i < 1769472) {
    float v;
    if (i < 442368) v = a[i];
    else if (i < 589824) v = b[i - 442368];
    else if (i < 1179648) v = c[i - 589824];
    else v = d[i - 1179648];
    o[i] = f2bf(v);
  } else if (i < 1769472 + 13824) {
    const int j = i - 1769472;
    const int tap = j / 1536;
    const int ch = j - tap * 1536;
    dwt[j] = dww[ch * 9 + tap];
  }
}

// ---------------------------------------------------------------------------
// LayerNorm -> bf16. REMAP=1: out token is windowed/rolled; src via roll(+4).
// ---------------------------------------------------------------------------
template <int REMAP>
__global__ __launch_bounds__(384) void ln_kernel(const float* __restrict__ x,
                                                 const float* __restrict__ g,
                                                 const float* __restrict__ b,
                                                 unsigned short* __restrict__ y) {
  __shared__ float red[2][6];
  const int t = blockIdx.x;
  size_t src;
  if (REMAP) {
    const int widx = t >> 6;
    const int n = t & 63;
    const int bb = widx >> 6;
    const int wh = (widx >> 3) & 7;
    const int ww = widx & 7;
    const int hp = wh * 8 + (n >> 3);
    const int wp = ww * 8 + (n & 7);
    const int hs = (hp + 4) & 63;
    const int wsrc = (wp + 4) & 63;
    src = (size_t)bb * 4096 + hs * 64 + wsrc;
  } else {
    src = (size_t)t;
  }
  const int tid = threadIdx.x;
  const float v = x[src * CCH + tid];
  float s = v, s2 = v * v;
#pragma unroll
  for (int o = 1; o < 64; o <<= 1) {
    s += __shfl_xor(s, o);
    s2 += __shfl_xor(s2, o);
  }
  const int wid = tid >> 6;
  if ((tid & 63) == 0) {
    red[0][wid] = s;
    red[1][wid] = s2;
  }
  __syncthreads();
  float ts = 0.f, ts2 = 0.f;
#pragma unroll
  for (int i = 0; i < 6; ++i) {
    ts += red[0][i];
    ts2 += red[1][i];
  }
  const float mean = ts * (1.0f / 384.0f);
  const float var = ts2 * (1.0f / 384.0f) - mean * mean;
  const float rstd = rsqrtf(var + 1e-5f);
  y[(size_t)t * CCH + tid] = f2bf((v - mean) * rstd * g[tid] + b[tid]);
}

// ---------------------------------------------------------------------------
// bf16 MFMA GEMM: C = A(MxK,bf16) @ W(NxK,bf16)^T + bias.
// 128x128 tile, 256 thr = 4 waves (2x2 of 64x64), 4x4 MFMA 16x16x32 per wave.
// Staging via global_load_lds width=16 (async, no VGPR round-trip).
// MODE 0: qkv  -> bf16 store (r*N+c)
// MODE 1: proj -> fp32, window-reverse+roll remap, Cout[dst] = Xres[dst]+val
// MODE 2: fc1  -> bf16, gelu(bn(val))
// MODE 3: fc2  -> fp32, Cout[r*N+c] += gelu(bn(val))
// ---------------------------------------------------------------------------
template <int MODE>
__global__ __launch_bounds__(256) void mfma_gemm(
    const unsigned short* __restrict__ A, const unsigned short* __restrict__ W,
    const float* __restrict__ bias, void* __restrict__ CoutV,
    const float* __restrict__ Xres, const float* __restrict__ bng,
    const float* __restrict__ bnb, int N, int K) {
  __shared__ __align__(16) unsigned short As[128 * 32];
  __shared__ __align__(16) unsigned short Bs[128 * 32];
  const int tid = threadIdx.x;
  const int wave = tid >> 6, lane = tid & 63;
  const int qd = lane >> 4, ln16 = lane & 15;
  const int wm = wave >> 1, wn = wave & 1;
  const int m0 = blockIdx.x * 128;
  const int n0 = blockIdx.y * 128;

  f32x4 acc[4][4];
#pragma unroll
  for (int i = 0; i < 4; ++i)
#pragma unroll
    for (int j = 0; j < 4; ++j) acc[i][j] = (f32x4){0.f, 0.f, 0.f, 0.f};

  const int r = tid >> 2;        // 0..63
  const int ck = (tid & 3) * 8;  // k element offset of 16B chunk

  const unsigned short* gA0 = A + (size_t)(m0 + r) * K + ck;
  const unsigned short* gA1 = A + (size_t)(m0 + 64 + r) * K + ck;
  const unsigned short* gB0 = W + (size_t)(n0 + r) * K + ck;
  const unsigned short* gB1 = W + (size_t)(n0 + 64 + r) * K + ck;
  unsigned short* lA0 = As + wave * 512;
  unsigned short* lA1 = As + 2048 + wave * 512;
  unsigned short* lB0 = Bs + wave * 512;
  unsigned short* lB1 = Bs + 2048 + wave * 512;

  for (int k0 = 0; k0 < K; k0 += 32) {
    __syncthreads();  // previous tile's compute done before LDS overwrite
    gl_lds16(gA0 + k0, lA0);
    gl_lds16(gA1 + k0, lA1);
    gl_lds16(gB0 + k0, lB0);
    gl_lds16(gB1 + k0, lB1);
    __syncthreads();  // drains vmcnt -> staged data visible
    short8 af[4], bfr[4];
#pragma unroll
    for (int mt = 0; mt < 4; ++mt)
      af[mt] = *(const short8*)&As[(wm * 64 + mt * 16 + ln16) * 32 + qd * 8];
#pragma unroll
    for (int nt = 0; nt < 4; ++nt)
      bfr[nt] = *(const short8*)&Bs[(wn * 64 + nt * 16 + ln16) * 32 + qd * 8];
#pragma unroll
    for (int mt = 0; mt < 4; ++mt)
#pragma unroll
      for (int nt = 0; nt < 4; ++nt)
        acc[mt][nt] = __builtin_amdgcn_mfma_f32_16x16x32_bf16(
            af[mt], bfr[nt], acc[mt][nt], 0, 0, 0);
  }

  const float RSQ = 0.99999500003749969f;  // 1/sqrt(1+1e-5)
#pragma unroll
  for (int mt = 0; mt < 4; ++mt) {
#pragma unroll
    for (int nt = 0; nt < 4; ++nt) {
      const int col = n0 + wn * 64 + nt * 16 + ln16;
      const int rbase = m0 + wm * 64 + mt * 16 + qd * 4;
#pragma unroll
      for (int rg = 0; rg < 4; ++rg) {
        const int row = rbase + rg;
        const float val = acc[mt][nt][rg] + bias[col];
        if (MODE == 0) {
          ((unsigned short*)CoutV)[(size_t)row * N + col] = f2bf(val);
        } else if (MODE == 1) {
          const int widx = row >> 6, n = row & 63;
          const int bb = widx >> 6, wh = (widx >> 3) & 7, wwi = widx & 7;
          const int hp = wh * 8 + (n >> 3), wp = wwi * 8 + (n & 7);
          const int hh = (hp + 4) & 63, wwp = (wp + 4) & 63;
          const size_t dst = ((size_t)bb * 4096 + hh * 64 + wwp) * CCH + col;
          ((float*)CoutV)[dst] = Xres[dst] + val;
        } else {
          const float vbn = val * (bng[col] * RSQ) + bnb[col];
          const float ge = gelu_exact(vbn);
          if (MODE == 2) {
            ((unsigned short*)CoutV)[(size_t)row * N + col] = f2bf(ge);
          } else {
            float* o = (float*)CoutV + (size_t)row * N + col;
            *o = *o + ge;
          }
        }
      }
    }
  }
}

// ---------------------------------------------------------------------------
// Slim attention: one block per (window-in-chunk, head). q/k/v from bf16
// qkv buffer (Mc x 1152). LDS ~42 KiB.
// ---------------------------------------------------------------------------
__global__ __launch_bounds__(256) void attn_kernel(
    const unsigned short* __restrict__ qkv, const float* __restrict__ rpb,
    unsigned short* __restrict__ ao) {
  __shared__ float qs[64][33];
  __shared__ float ks[64][33];
  __shared__ float vs[64][33];
  __shared__ float at[64][65];
  const int wloc = blockIdx.x / 12;  // window within chunk (0..255)
  const int head = blockIdx.x % 12;
  const int tid = threadIdx.x;
  const int wpos = wloc & 63;  // window position in image
  const int wh = (wpos >> 3) & 7, ww = wpos & 7;

  {
    const int n = tid >> 2, d0 = (tid & 3) * 8;
    const float scale = 0.17677669529663687f;  // 32^-0.5
    const size_t base = ((size_t)wloc * 64 + n) * 1152 + head * 32 + d0;
    const unsigned short* qp = qkv + base;
    const unsigned short* kp = qkv + base + 384;
    const unsigned short* vp = qkv + base + 768;
#pragma unroll
    for (int j = 0; j < 8; ++j) qs[n][d0 + j] = bf2f(qp[j]) * scale;
#pragma unroll
    for (int j = 0; j < 8; ++j) ks[n][d0 + j] = bf2f(kp[j]);
#pragma unroll
    for (int j = 0; j < 8; ++j) vs[n][d0 + j] = bf2f(vp[j]);
  }
  __syncthreads();

#pragma unroll
  for (int i = 0; i < 16; ++i) {
    const int e = tid + i * 256;
    const int n = e >> 6, m = e & 63;
    float a = 0.f;
#pragma unroll
    for (int d = 0; d < 32; ++d) a += qs[n][d] * ks[m][d];
    const int cn = 15 * (n >> 3) + (n & 7);
    const int mf = 63 - m;
    const int cm = 15 * (mf >> 3) + (mf & 7);
    a += rpb[(cn + cm) * 12 + head];
    const int hn = wh * 8 + (n >> 3), wn_ = ww * 8 + (n & 7);
    const int hm = wh * 8 + (m >> 3), wmm = ww * 8 + (m & 7);
    if (region_label(hn) * 3 + region_label(wn_) !=
        region_label(hm) * 3 + region_label(wmm))
      a -= 100.f;
    at[n][m] = a;
  }
  __syncthreads();

  {
    const int row = tid >> 2, p = tid & 3;
    float mx = -1e30f;
    float ev[16];
#pragma unroll
    for (int j = 0; j < 16; ++j) mx = fmaxf(mx, at[row][p * 16 + j]);
    mx = fmaxf(mx, __shfl_xor(mx, 1));
    mx = fmaxf(mx, __shfl_xor(mx, 2));
    float sum = 0.f;
#pragma unroll
    for (int j = 0; j < 16; ++j) {
      ev[j] = expf(at[row][p * 16 + j] - mx);
      sum += ev[j];
    }
    sum += __shfl_xor(sum, 1);
    sum += __shfl_xor(sum, 2);
    const float inv = 1.0f / sum;
#pragma unroll
    for (int j = 0; j < 16; ++j) at[row][p * 16 + j] = ev[j] * inv;
  }
  __syncthreads();

#pragma unroll
  for (int i = 0; i < 8; ++i) {
    const int e = tid + i * 256;
    const int n = e >> 5, d = e & 31;
    float a = 0.f;
#pragma unroll
    for (int m = 0; m < 64; ++m) a += at[n][m] * vs[m][d];
    ao[((size_t)wloc * 64 + n) * CCH + head * 32 + d] = f2bf(a);
  }
}

// ---------------------------------------------------------------------------
// Depthwise 3x3 SAME + bias + BN2 + GELU, bf16 in/out, 8 channels/thread.
// dwt is [tap][1536] fp32. Grid covers 16384 pixels x 192 channel-groups.
// ---------------------------------------------------------------------------
__global__ __launch_bounds__(256) void dw_kernel(
    const unsigned short* __restrict__ z1, const float* __restrict__ dwt,
    const float* __restrict__ dwb, const float* __restrict__ bn2g,
    const float* __restrict__ bn2b, unsigned short* __restrict__ z2) {
  const int g = blockIdx.x * 256 + threadIdx.x;  // 0..3145727
  const int pix = g / 192;
  const int cg = g - pix * 192;
  const int c0 = cg * 8;
  const int p = pix & 4095;
  const int h = p >> 6, w = p & 63;
  const unsigned short* zb = z1 + (size_t)(pix >> 12) * 4096 * HIDCH;

  float a[8];
  {
    const float4 b0 = *(const float4*)&dwb[c0];
    const float4 b1 = *(const float4*)&dwb[c0 + 4];
    a[0] = b0.x; a[1] = b0.y; a[2] = b0.z; a[3] = b0.w;
    a[4] = b1.x; a[5] = b1.y; a[6] = b1.z; a[7] = b1.w;
  }
#pragma unroll
  for (int dh = -1; dh <= 1; ++dh) {
    const int hh = h + dh;
    if (hh < 0 || hh > 63) continue;
#pragma unroll
    for (int dx = -1; dx <= 1; ++dx) {
      const int wn = w + dx;
      if (wn < 0 || wn > 63) continue;
      const int tap = (dh + 1) * 3 + (dx + 1);
      const int4 zv = *(const int4*)&zb[((size_t)hh * 64 + wn) * HIDCH + c0];
      const float* wp = &dwt[tap * HIDCH + c0];
      const float4 w0 = *(const float4*)wp;
      const float4 w1 = *(const float4*)(wp + 4);
      a[0] += bf2f((unsigned short)(zv.x & 0xFFFF)) * w0.x;
      a[1] += bf2f((unsigned short)(((unsigned)zv.x) >> 16)) * w0.y;
      a[2] += bf2f((unsigned short)(zv.y & 0xFFFF)) * w0.z;
      a[3] += bf2f((unsigned short)(((unsigned)zv.y) >> 16)) * w0.w;
      a[4] += bf2f((unsigned short)(zv.z & 0xFFFF)) * w1.x;
      a[5] += bf2f((unsigned short)(((unsigned)zv.z) >> 16)) * w1.y;
      a[6] += bf2f((unsigned short)(zv.w & 0xFFFF)) * w1.z;
      a[7] += bf2f((unsigned short)(((unsigned)zv.w) >> 16)) * w1.w;
    }
  }
  const float RSQ = 0.99999500003749969f;
  const float4 g0 = *(const float4*)&bn2g[c0];
  const float4 g1 = *(const float4*)&bn2g[c0 + 4];
  const float4 bb0 = *(const float4*)&bn2b[c0];
  const float4 bb1 = *(const float4*)&bn2b[c0 + 4];
  const float gs[8] = {g0.x, g0.y, g0.z, g0.w, g1.x, g1.y, g1.z, g1.w};
  const float bs[8] = {bb0.x, bb0.y, bb0.z, bb0.w, bb1.x, bb1.y, bb1.z, bb1.w};
  unsigned pk[4];
#pragma unroll
  for (int i = 0; i < 4; ++i) {
    const float v0 = gelu_exact(a[2 * i] * (gs[2 * i] * RSQ) + bs[2 * i]);
    const float v1 =
        gelu_exact(a[2 * i + 1] * (gs[2 * i + 1] * RSQ) + bs[2 * i + 1]);
    pk[i] = (unsigned)f2bf(v0) | ((unsigned)f2bf(v1) << 16);
  }
  int4 st;
  st.x = pk[0]; st.y = pk[1]; st.z = pk[2]; st.w = pk[3];
  *(int4*)&z2[(size_t)pix * HIDCH + c0] = st;
}

extern "C" void kernel_launch(void* const* d_in, const int* in_sizes, int n_in,
                              void* d_out, int out_size, void* d_ws,
                              size_t ws_size, hipStream_t stream) {
  const float* x = (const float*)d_in[0];
  const float* ln1_g = (const float*)d_in[3];
  const float* ln1_b = (const float*)d_in[4];
  const float* qkv_w = (const float*)d_in[5];
  const float* qkv_b = (const float*)d_in[6];
  const float* rpb = (const float*)d_in[7];
  const float* proj_w = (const float*)d_in[8];
  const float* proj_b = (const float*)d_in[9];
  const float* ln2_g = (const float*)d_in[10];
  const float* ln2_b = (const float*)d_in[11];
  const float* fc1_w = (const float*)d_in[12];
  const float* fc1_b = (const float*)d_in[13];
  const float* bn1_g = (const float*)d_in[14];
  const float* bn1_b = (const float*)d_in[15];
  const float* dw_w = (const float*)d_in[16];
  const float* dw_b = (const float*)d_in[17];
  const float* bn2_g = (const float*)d_in[18];
  const float* bn2_b = (const float*)d_in[19];
  const float* fc2_w = (const float*)d_in[20];
  const float* fc2_b = (const float*)d_in[21];
  const float* bn3_g = (const float*)d_in[22];
  const float* bn3_b = (const float*)d_in[23];
  float* out = (float*)d_out;

  char* ws = (char*)d_ws;
  unsigned short* wsA = (unsigned short*)ws;                // 50.3 MB
  unsigned short* wsAO = (unsigned short*)(ws + 50331648);  // 50.3 MB
  unsigned short* wsQ = (unsigned short*)(ws + 100663296);  // 50.3 MB
  unsigned short* wbf = (unsigned short*)(ws + 150994944);  // 3.5 MB
  float* dwt = (float*)(ws + 154533888);                    // 55 KB
  unsigned short* w_qkv = wbf;
  unsigned short* w_proj = wbf + 442368;
  unsigned short* w_fc1 = wbf + 589824;
  unsigned short* w_fc2 = wbf + 1179648;

  // 0. weights -> bf16 (+ dw transpose to fp32 [9][1536])
  convw_kernel<<<6966, 256, 0, stream>>>(qkv_w, proj_w, fc1_w, fc2_w, dw_w,
                                         wbf, dwt);
  // 1. LN1 + roll + window partition
  ln_kernel<1><<<65536, 384, 0, stream>>>(x, ln1_g, ln1_b, wsA);
  // 2. QKV GEMM + attention per 4-batch chunk (16384 tokens)
  for (int cb = 0; cb < 4; ++cb) {
    mfma_gemm<0><<<dim3(128, 9), 256, 0, stream>>>(
        wsA + (size_t)cb * 16384 * CCH, w_qkv, qkv_b, wsQ, nullptr, nullptr,
        nullptr, 1152, CCH);
    attn_kernel<<<256 * 12, 256, 0, stream>>>(wsQ, rpb,
                                              wsAO + (size_t)cb * 16384 * CCH);
  }
  // 3. proj + unwindow + unroll + residual -> d_out
  mfma_gemm<1><<<dim3(512, 3), 256, 0, stream>>>(wsAO, w_proj, proj_b, out, x,
                                                 nullptr, nullptr, CCH, CCH);
  // 4. LN2 -> wsA
  ln_kernel<0><<<65536, 384, 0, stream>>>(out, ln2_g, ln2_b, wsA);
  // 5. MLP per 4-batch chunk; z1 = wsAO, z2 = wsQ
  for (int cb = 0; cb < 4; ++cb) {
    mfma_gemm<2><<<dim3(128, 12), 256, 0, stream>>>(
        wsA + (size_t)cb * 16384 * CCH, w_fc1, fc1_b, wsAO, nullptr, bn1_g,
        bn1_b, HIDCH, CCH);
    dw_kernel<<<12288, 256, 0, stream>>>(wsAO, dwt, dw_b, bn2_g, bn2_b, wsQ);
    mfma_gemm<3><<<dim3(128, 3), 256, 0, stream>>>(
        wsQ, w_fc2, fc2_b, out + (size_t)cb * 16384 * CCH, nullptr, bn3_g,
        bn3_b, CCH, HIDCH);
  }
}